// Round 4
// baseline (993.104 us; speedup 1.0000x reference)
//
#include <hip/hip_runtime.h>
#include <stdint.h>

#define NBATCH 16384
#define TT     20
#define CC     256
#define LDK    264   // LDS row stride (bf16 elems); 528B rows keep 16B alignment
#define BPB    32    // batches per block
#define NT     512   // threads per block (8 waves)

typedef __bf16 bf16x8 __attribute__((ext_vector_type(8)));
typedef float  f32x4  __attribute__((ext_vector_type(4)));

// Active-column tables from tb_mask(T=20, win=3):
// t=0,1:{0,1,2}  t=2:{0,1,2,3}  t=3..15:{t,t+1}  t=16: uniform 1/20  t=17..19:{17,18,19}
__constant__ int8_t c_CNT[TT]     = {3,3,4,2,2,2,2,2,2,2,2,2,2,2,2,2,0,3,3,3};
__constant__ int8_t c_OFF[TT]     = {0,3,6,10,12,14,16,18,20,22,24,26,28,30,32,34,0,36,39,42};
__constant__ int8_t c_COLS[TT][4] = {
    {0,1,2,0},{0,1,2,0},{0,1,2,3},
    {3,4,0,0},{4,5,0,0},{5,6,0,0},{6,7,0,0},{7,8,0,0},{8,9,0,0},
    {9,10,0,0},{10,11,0,0},{11,12,0,0},{12,13,0,0},{13,14,0,0},
    {14,15,0,0},{15,16,0,0},{0,0,0,0},
    {17,18,19,0},{17,18,19,0},{17,18,19,0}};
__constant__ int8_t c_PT[45] = {0,0,0,1,1,1,2,2,2,2,3,3,4,4,5,5,6,6,7,7,8,8,9,9,
                                10,10,11,11,12,12,13,13,14,14,15,15,17,17,17,18,18,18,19,19,19};
__constant__ int8_t c_PS[45] = {0,1,2,0,1,2,0,1,2,3,3,4,4,5,5,6,6,7,7,8,8,9,9,10,
                                10,11,11,12,12,13,13,14,14,15,15,16,17,18,19,17,18,19,17,18,19};

__device__ __forceinline__ uint16_t f2bf(float f) {
    __bf16 b = (__bf16)f;
    return __builtin_bit_cast(uint16_t, b);
}
__device__ __forceinline__ uint32_t pk2(float a, float b) {
    return (uint32_t)f2bf(a) | ((uint32_t)f2bf(b) << 16);
}
__device__ __forceinline__ float bflo(uint32_t u) { return __builtin_bit_cast(float, u << 16); }
__device__ __forceinline__ float bfhi(uint32_t u) { return __builtin_bit_cast(float, u & 0xffff0000u); }

// Prep: mqkT[n][k] = sum_h Wk[h,n]*Wq[h,k] / 16 ;  wvb[n][k] = bf16(Wv[n][k])
__global__ void prep_kernel(const float* __restrict__ Wq, const float* __restrict__ Wk,
                            const float* __restrict__ Wv, uint16_t* __restrict__ mqkT,
                            uint16_t* __restrict__ wvb) {
    const int n = blockIdx.x;
    const int k = threadIdx.x;
    float acc = 0.f;
    for (int h = 0; h < CC; ++h)
        acc = fmaf(Wk[h * CC + n], Wq[h * CC + k], acc);
    mqkT[n * CC + k] = f2bf(acc * 0.0625f);
    wvb[n * CC + k]  = f2bf(Wv[n * CC + k]);
}

// D layout (m89): col = lane&15, row = 4*(lane>>4)+i.  32-col slice at wcol. Guard rows >= TT.
__device__ __forceinline__ void storeD(uint16_t* __restrict__ sD, int wcol, int lane,
                                       f32x4 acc[2][2]) {
    const int drow = (lane >> 4) << 2;
    const int dcol = lane & 15;
#pragma unroll
    for (int rt = 0; rt < 2; ++rt)
#pragma unroll
        for (int ct = 0; ct < 2; ++ct)
#pragma unroll
            for (int j = 0; j < 4; ++j) {
                int row = rt * 16 + drow + j;
                if (row < TT)
                    sD[row * LDK + (wcol + ct * 16 + dcol)] = f2bf(acc[rt][ct][j]);
            }
}

__device__ __forceinline__ void acc8(float* o, uint4 uv, float wgt) {
    o[0] = fmaf(bflo(uv.x), wgt, o[0]);
    o[1] = fmaf(bfhi(uv.x), wgt, o[1]);
    o[2] = fmaf(bflo(uv.y), wgt, o[2]);
    o[3] = fmaf(bfhi(uv.y), wgt, o[3]);
    o[4] = fmaf(bflo(uv.z), wgt, o[4]);
    o[5] = fmaf(bfhi(uv.z), wgt, o[5]);
    o[6] = fmaf(bflo(uv.w), wgt, o[6]);
    o[7] = fmaf(bfhi(uv.w), wgt, o[7]);
}

__global__ __launch_bounds__(NT, 4)
void attn_main(const float* __restrict__ f1g, const float* __restrict__ f2g,
               const uint16_t* __restrict__ mqkT, const uint16_t* __restrict__ wvb,
               float* __restrict__ outg) {
    __shared__ uint16_t sF1[2][TT * LDK];   // feat1 bf16, double-buffered
    __shared__ uint16_t sF2[2][TT * LDK];   // feat2 bf16, double-buffered
    __shared__ uint16_t sT1[TT * LDK];      // t1 = feat1*Mqk
    __shared__ uint16_t sV [TT * LDK];      // v  = feat2*Wv^T
    __shared__ float    s_sim[45];

    const int tid  = threadIdx.x;
    const int lane = tid & 63;
    const int w    = tid >> 6;            // 0..7
    const int lrow = lane & 15;
    const int lk8  = (lane >> 4) << 3;
    const int wcol = w << 5;              // each wave owns 32 output cols

    // ---- B fragments resident in VGPRs for the whole block (128 VGPRs) ----
    bf16x8 Bq[2][8], Bv[2][8];
#pragma unroll
    for (int ct = 0; ct < 2; ++ct)
#pragma unroll
        for (int kk = 0; kk < 8; ++kk) {
            const int n = wcol + ct * 16 + lrow;
            Bq[ct][kk] = __builtin_bit_cast(bf16x8, *(const uint4*)(mqkT + n * CC + kk * 32 + lk8));
            Bv[ct][kk] = __builtin_bit_cast(bf16x8, *(const uint4*)(wvb  + n * CC + kk * 32 + lk8));
        }

    const size_t base = (size_t)blockIdx.x * BPB * TT * CC;

    // ---- prologue: stage batch 0 (2560 float4 slots: f1 0..1279, f2 1280..2559) ----
    {
        const float* f1 = f1g + base;
        const float* f2 = f2g + base;
#pragma unroll
        for (int j = 0; j < 5; ++j) {
            int s = tid + j * NT;
            bool is1 = s < 1280;
            int sl = is1 ? s : s - 1280;
            float4 v = *(const float4*)((is1 ? f1 : f2) + (sl << 2));
            uint2 u; u.x = pk2(v.x, v.y); u.y = pk2(v.z, v.w);
            uint16_t* dst = is1 ? sF1[0] : sF2[0];
            *(uint2*)&dst[(sl >> 6) * LDK + ((sl & 63) << 2)] = u;
        }
    }
    __syncthreads();

    const int r0 = lrow;
    const int r1 = (16 + lrow < TT) ? (16 + lrow) : (TT - 1);

    for (int i = 0; i < BPB; ++i) {
        const int cur = i & 1, nxt = cur ^ 1;
        const bool hasNext = (i + 1 < BPB);

        // ---- phase A: issue f1 prefetch, GEMMs from LDS, store t1/v, write f1 stage ----
        float4 pf1[3];
        if (hasNext) {
            const float* f1n = f1g + base + (size_t)(i + 1) * TT * CC;
#pragma unroll
            for (int j = 0; j < 3; ++j) {
                int s = tid + j * NT;
                if (s < 1280) pf1[j] = *(const float4*)(f1n + (s << 2));
            }
        }

        f32x4 a1[2][2], a2[2][2];
#pragma unroll
        for (int p = 0; p < 2; ++p)
#pragma unroll
            for (int q = 0; q < 2; ++q) {
                a1[p][q] = f32x4{0.f, 0.f, 0.f, 0.f};
                a2[p][q] = f32x4{0.f, 0.f, 0.f, 0.f};
            }
        const uint16_t* A1 = sF1[cur];
        const uint16_t* A2 = sF2[cur];
#pragma unroll
        for (int kk = 0; kk < 8; ++kk) {
            bf16x8 x0 = __builtin_bit_cast(bf16x8, *(const uint4*)(A1 + r0 * LDK + kk * 32 + lk8));
            bf16x8 x1 = __builtin_bit_cast(bf16x8, *(const uint4*)(A1 + r1 * LDK + kk * 32 + lk8));
            bf16x8 y0 = __builtin_bit_cast(bf16x8, *(const uint4*)(A2 + r0 * LDK + kk * 32 + lk8));
            bf16x8 y1 = __builtin_bit_cast(bf16x8, *(const uint4*)(A2 + r1 * LDK + kk * 32 + lk8));
            a1[0][0] = __builtin_amdgcn_mfma_f32_16x16x32_bf16(x0, Bq[0][kk], a1[0][0], 0, 0, 0);
            a1[0][1] = __builtin_amdgcn_mfma_f32_16x16x32_bf16(x0, Bq[1][kk], a1[0][1], 0, 0, 0);
            a1[1][0] = __builtin_amdgcn_mfma_f32_16x16x32_bf16(x1, Bq[0][kk], a1[1][0], 0, 0, 0);
            a1[1][1] = __builtin_amdgcn_mfma_f32_16x16x32_bf16(x1, Bq[1][kk], a1[1][1], 0, 0, 0);
            a2[0][0] = __builtin_amdgcn_mfma_f32_16x16x32_bf16(y0, Bv[0][kk], a2[0][0], 0, 0, 0);
            a2[0][1] = __builtin_amdgcn_mfma_f32_16x16x32_bf16(y0, Bv[1][kk], a2[0][1], 0, 0, 0);
            a2[1][0] = __builtin_amdgcn_mfma_f32_16x16x32_bf16(y1, Bv[0][kk], a2[1][0], 0, 0, 0);
            a2[1][1] = __builtin_amdgcn_mfma_f32_16x16x32_bf16(y1, Bv[1][kk], a2[1][1], 0, 0, 0);
        }
        storeD(sT1, wcol, lane, a1);
        storeD(sV,  wcol, lane, a2);

        if (hasNext) {
#pragma unroll
            for (int j = 0; j < 3; ++j) {
                int s = tid + j * NT;
                if (s < 1280) {
                    uint2 u; u.x = pk2(pf1[j].x, pf1[j].y); u.y = pk2(pf1[j].z, pf1[j].w);
                    *(uint2*)&sF1[nxt][(s >> 6) * LDK + ((s & 63) << 2)] = u;
                }
            }
        }
        __syncthreads();   // bar1: t1, v, f1-next visible

        // ---- phase B: issue f2 prefetch; sparse sim (45 dots x 8 threads x 32 ch) ----
        float4 pf2[3];
        if (hasNext) {
            const float* f2n = f2g + base + (size_t)(i + 1) * TT * CC;
#pragma unroll
            for (int j = 0; j < 3; ++j) {
                int s = tid + j * NT;
                if (s < 1280) pf2[j] = *(const float4*)(f2n + (s << 2));
            }
        }
        if (tid < 360) {
            int d = tid >> 3, p = tid & 7;
            int tt = c_PT[d], ss = c_PS[d];
            const uint16_t* ap = sT1 + tt * LDK + (p << 3);
            const uint16_t* bp = sF2[cur] + ss * LDK + (p << 3);
            float da = 0.f;
#pragma unroll
            for (int c = 0; c < 256; c += 64) {     // chunks at p*16B + j*128B: conflict-free
                uint4 ua = *(const uint4*)(ap + c);
                uint4 ub = *(const uint4*)(bp + c);
                da = fmaf(bflo(ua.x), bflo(ub.x), da);
                da = fmaf(bfhi(ua.x), bfhi(ub.x), da);
                da = fmaf(bflo(ua.y), bflo(ub.y), da);
                da = fmaf(bfhi(ua.y), bfhi(ub.y), da);
                da = fmaf(bflo(ua.z), bflo(ub.z), da);
                da = fmaf(bfhi(ua.z), bfhi(ub.z), da);
                da = fmaf(bflo(ua.w), bflo(ub.w), da);
                da = fmaf(bfhi(ua.w), bfhi(ub.w), da);
            }
            da += __shfl_xor(da, 1);
            da += __shfl_xor(da, 2);
            da += __shfl_xor(da, 4);
            if (p == 0) s_sim[d] = da;
        }
        __syncthreads();   // bar2: s_sim visible

        // ---- phase C: inline softmax + combine + coalesced out store; write f2 stage ----
        const size_t ob = base + (size_t)i * TT * CC;
#pragma unroll
        for (int pass = 0; pass < 2; ++pass) {
            int u = tid + (pass << 9);
            if (u < 640) {
                int r  = u >> 5;
                int ch = (u & 31) << 3;
                float o[8] = {0.f, 0.f, 0.f, 0.f, 0.f, 0.f, 0.f, 0.f};
                if (r == 16) {
                    const uint16_t* vb = &sV[ch];
#pragma unroll
                    for (int ss = 0; ss < TT; ++ss)
                        acc8(o, *(const uint4*)(vb + ss * LDK), 0.05f);
                } else {
                    int cnt = c_CNT[r];
                    int off = c_OFF[r];
                    float m = -1e30f;
#pragma unroll
                    for (int j = 0; j < 4; ++j)
                        if (j < cnt) m = fmaxf(m, s_sim[off + j]);
                    float e[4] = {0.f, 0.f, 0.f, 0.f};
                    float sum = 0.f;
#pragma unroll
                    for (int j = 0; j < 4; ++j)
                        if (j < cnt) { e[j] = __expf(s_sim[off + j] - m); sum += e[j]; }
                    float inv = 1.f / sum;
#pragma unroll
                    for (int j = 0; j < 4; ++j)
                        if (j < cnt)
                            acc8(o, *(const uint4*)&sV[c_COLS[r][j] * LDK + ch], e[j] * inv);
                }
                float* op = outg + ob + (size_t)r * CC + ch;
                *(float4*)op       = make_float4(o[0], o[1], o[2], o[3]);
                *(float4*)(op + 4) = make_float4(o[4], o[5], o[6], o[7]);
            }
        }
        if (hasNext) {
#pragma unroll
            for (int j = 0; j < 3; ++j) {
                int s = tid + j * NT;
                if (s < 1280) {
                    uint2 u; u.x = pk2(pf2[j].x, pf2[j].y); u.y = pk2(pf2[j].z, pf2[j].w);
                    *(uint2*)&sF2[nxt][(s >> 6) * LDK + ((s & 63) << 2)] = u;
                }
            }
        }
        __syncthreads();   // bar3: sV/sT1/s_sim free; f2-next visible
    }
}

extern "C" void kernel_launch(void* const* d_in, const int* in_sizes, int n_in,
                              void* d_out, int out_size, void* d_ws, size_t ws_size,
                              hipStream_t stream) {
    const float* feat1 = (const float*)d_in[0];
    const float* feat2 = (const float*)d_in[1];
    const float* Wq    = (const float*)d_in[2];
    const float* Wk    = (const float*)d_in[3];
    const float* Wv    = (const float*)d_in[4];
    uint16_t* mqkT = (uint16_t*)d_ws;
    uint16_t* wvb  = mqkT + CC * CC;

    prep_kernel<<<CC, CC, 0, stream>>>(Wq, Wk, Wv, mqkT, wvb);
    attn_main<<<NBATCH / BPB, NT, 0, stream>>>(feat1, feat2, mqkT, wvb, (float*)d_out);
}

// Round 5
// 481.188 us; speedup vs baseline: 2.0639x; 2.0639x over previous
//
#include <hip/hip_runtime.h>
#include <stdint.h>

#define NBATCH 16384
#define TT     20
#define CC     256
#define LDK    264   // LDS row stride (bf16 elems)
#define NT     256   // 4 waves

typedef __bf16 bf16x8 __attribute__((ext_vector_type(8)));
typedef float  f32x4  __attribute__((ext_vector_type(4)));

// Active-column tables from tb_mask(T=20, win=3):
// t=0,1:{0,1,2}  t=2:{0,1,2,3}  t=3..15:{t,t+1}  t=16: uniform 1/20  t=17..19:{17,18,19}
__constant__ int8_t c_CNT[TT]     = {3,3,4,2,2,2,2,2,2,2,2,2,2,2,2,2,0,3,3,3};
__constant__ int8_t c_OFF[TT]     = {0,3,6,10,12,14,16,18,20,22,24,26,28,30,32,34,0,36,39,42};
__constant__ int8_t c_COLS[TT][4] = {
    {0,1,2,0},{0,1,2,0},{0,1,2,3},
    {3,4,0,0},{4,5,0,0},{5,6,0,0},{6,7,0,0},{7,8,0,0},{8,9,0,0},
    {9,10,0,0},{10,11,0,0},{11,12,0,0},{12,13,0,0},{13,14,0,0},
    {14,15,0,0},{15,16,0,0},{0,0,0,0},
    {17,18,19,0},{17,18,19,0},{17,18,19,0}};
__constant__ int8_t c_PT[45] = {0,0,0,1,1,1,2,2,2,2,3,3,4,4,5,5,6,6,7,7,8,8,9,9,
                                10,10,11,11,12,12,13,13,14,14,15,15,17,17,17,18,18,18,19,19,19};
__constant__ int8_t c_PS[45] = {0,1,2,0,1,2,0,1,2,3,3,4,4,5,5,6,6,7,7,8,8,9,9,10,
                                10,11,11,12,12,13,13,14,14,15,15,16,17,18,19,17,18,19,17,18,19};

__device__ __forceinline__ uint16_t f2bf(float f) {
    __bf16 b = (__bf16)f;
    return __builtin_bit_cast(uint16_t, b);
}
__device__ __forceinline__ uint32_t pk2(float a, float b) {
    return (uint32_t)f2bf(a) | ((uint32_t)f2bf(b) << 16);
}
__device__ __forceinline__ float bflo(uint32_t u) { return __builtin_bit_cast(float, u << 16); }
__device__ __forceinline__ float bfhi(uint32_t u) { return __builtin_bit_cast(float, u & 0xffff0000u); }

// prep1: mqkT[n][k] = sum_h Wk[h,n]*Wq[h,k] / 16 ;  wvb[n][k] = bf16(Wv[n][k])
__global__ void prep1_kernel(const float* __restrict__ Wq, const float* __restrict__ Wk,
                             const float* __restrict__ Wv, uint16_t* __restrict__ mqkT,
                             uint16_t* __restrict__ wvb) {
    const int n = blockIdx.x;
    const int k = threadIdx.x;
    float acc = 0.f;
    for (int h = 0; h < CC; ++h)
        acc = fmaf(Wk[h * CC + n], Wq[h * CC + k], acc);
    mqkT[n * CC + k] = f2bf(acc * 0.0625f);
    wvb[n * CC + k]  = f2bf(Wv[n * CC + k]);
}

// prep2: swizzle B^T tables into per-wave MFMA fragment order so each fragment
// is one fully-coalesced 1KB load:  dst[((w*32 + kk*4 + ct)*64 + lane)*8 .. +8)
//   = src[(w*64 + ct*16 + (lane&15)) * CC + kk*32 + ((lane>>4)<<3) .. +8)
__global__ void prep2_kernel(const uint16_t* __restrict__ mqkT, const uint16_t* __restrict__ wvb,
                             uint16_t* __restrict__ BqS, uint16_t* __restrict__ BvS) {
    const int bid = blockIdx.x;          // 0..63 : m*32 + w*8 + kk
    const int m  = bid >> 5;
    const int w  = (bid >> 3) & 3;
    const int kk = bid & 7;
    const int ct   = threadIdx.x >> 6;
    const int lane = threadIdx.x & 63;
    const uint16_t* src = m ? wvb : mqkT;
    uint16_t*       dst = m ? BvS : BqS;
    const int n   = w * 64 + ct * 16 + (lane & 15);
    const int col = kk * 32 + ((lane >> 4) << 3);
    uint4 v = *(const uint4*)(src + n * CC + col);
    *(uint4*)(dst + ((size_t)((w * 32 + kk * 4 + ct) * 64 + lane) << 3)) = v;
}

// D layout (m89): col = lane&15, row = 4*(lane>>4)+j.  64-col wave panel at wcol.
__device__ __forceinline__ void storeD(uint16_t* __restrict__ sD, int wcol, int lane,
                                       f32x4 acc[2][4]) {
    const int drow = (lane >> 4) << 2;
    const int dcol = lane & 15;
#pragma unroll
    for (int rt = 0; rt < 2; ++rt)
#pragma unroll
        for (int ct = 0; ct < 4; ++ct)
#pragma unroll
            for (int j = 0; j < 4; ++j) {
                int row = rt * 16 + drow + j;
                if (row < TT)
                    sD[row * LDK + (wcol + ct * 16 + dcol)] = f2bf(acc[rt][ct][j]);
            }
}

__device__ __forceinline__ void acc8(float* o, uint4 uv, float wgt) {
    o[0] = fmaf(bflo(uv.x), wgt, o[0]);
    o[1] = fmaf(bfhi(uv.x), wgt, o[1]);
    o[2] = fmaf(bflo(uv.y), wgt, o[2]);
    o[3] = fmaf(bfhi(uv.y), wgt, o[3]);
    o[4] = fmaf(bflo(uv.z), wgt, o[4]);
    o[5] = fmaf(bfhi(uv.z), wgt, o[5]);
    o[6] = fmaf(bflo(uv.w), wgt, o[6]);
    o[7] = fmaf(bfhi(uv.w), wgt, o[7]);
}

__global__ __launch_bounds__(NT, 5)
void attn_main(const float* __restrict__ f1g, const float* __restrict__ f2g,
               const uint16_t* __restrict__ BqS, const uint16_t* __restrict__ BvS,
               float* __restrict__ outg) {
    __shared__ uint16_t sF1[TT * LDK];   // feat1 -> (later) v
    __shared__ uint16_t sF2[TT * LDK];   // feat2
    __shared__ uint16_t sT1[TT * LDK];   // t1 = feat1*Mqk
    __shared__ float    s_sim[45];

    const int tid  = threadIdx.x;
    const int lane = tid & 63;
    const int w    = tid >> 6;            // 0..3, wave owns 64 output cols
    const int lrow = lane & 15;
    const size_t base = (size_t)blockIdx.x * TT * CC;
    const float* f1 = f1g + base;
    const float* f2 = f2g + base;

    // ---- stage feat1+feat2 -> LDS bf16 (coalesced float4) ----
#pragma unroll
    for (int j = 0; j < 5; ++j) {
        int s  = tid + (j << 8);          // 0..1279 float4 slots per tensor
        int r  = s >> 6;
        int c4 = (s & 63) << 2;
        float4 a = *(const float4*)(f1 + (s << 2));
        float4 b = *(const float4*)(f2 + (s << 2));
        uint2 ua; ua.x = pk2(a.x, a.y); ua.y = pk2(a.z, a.w);
        uint2 ub; ub.x = pk2(b.x, b.y); ub.y = pk2(b.z, b.w);
        *(uint2*)&sF1[r * LDK + c4] = ua;
        *(uint2*)&sF2[r * LDK + c4] = ub;
    }
    __syncthreads();                      // B1

    const int r0 = lrow;
    const int r1 = (16 + lrow < TT) ? (16 + lrow) : (TT - 1);
    const uint16_t* bq = BqS + ((size_t)w << 14);   // w*32*64*8 uint16
    const uint16_t* bv = BvS + ((size_t)w << 14);

    // ---- GEMM1: t1 = feat1 * Mqk (A from LDS, B coalesced-streamed from L2) ----
    f32x4 acc[2][4];
#pragma unroll
    for (int p = 0; p < 2; ++p)
#pragma unroll
        for (int q = 0; q < 4; ++q)
            acc[p][q] = f32x4{0.f, 0.f, 0.f, 0.f};
#pragma unroll
    for (int kk = 0; kk < 8; ++kk) {
        const int ko = kk * 32 + ((lane >> 4) << 3);
        bf16x8 x0 = __builtin_bit_cast(bf16x8, *(const uint4*)(sF1 + r0 * LDK + ko));
        bf16x8 x1 = __builtin_bit_cast(bf16x8, *(const uint4*)(sF1 + r1 * LDK + ko));
        bf16x8 bf[4];
#pragma unroll
        for (int ct = 0; ct < 4; ++ct)
            bf[ct] = __builtin_bit_cast(bf16x8,
                *(const uint4*)(bq + (((kk << 2) + ct) * 64 + lane) * 8));
#pragma unroll
        for (int ct = 0; ct < 4; ++ct) {
            acc[0][ct] = __builtin_amdgcn_mfma_f32_16x16x32_bf16(x0, bf[ct], acc[0][ct], 0, 0, 0);
            acc[1][ct] = __builtin_amdgcn_mfma_f32_16x16x32_bf16(x1, bf[ct], acc[1][ct], 0, 0, 0);
        }
    }
    storeD(sT1, w << 6, lane, acc);
    __syncthreads();                      // B2: t1 visible; sF1 reads done

    // ---- sim (45 dots x 4 threads x 64ch) + GEMM2: v = feat2*Wv^T -> sF1 ----
    if (tid < 180) {
        int d = tid >> 2, p = tid & 3;
        int tt = c_PT[d], ss = c_PS[d];
        const uint16_t* ap = sT1 + tt * LDK + (p << 3);
        const uint16_t* bp = sF2 + ss * LDK + (p << 3);
        float da = 0.f;
#pragma unroll
        for (int c = 0; c < 256; c += 32) {   // 16B chunks at p*16B + c*64B
            uint4 ua = *(const uint4*)(ap + c);
            uint4 ub = *(const uint4*)(bp + c);
            da = fmaf(bflo(ua.x), bflo(ub.x), da);
            da = fmaf(bfhi(ua.x), bfhi(ub.x), da);
            da = fmaf(bflo(ua.y), bflo(ub.y), da);
            da = fmaf(bfhi(ua.y), bfhi(ub.y), da);
            da = fmaf(bflo(ua.z), bflo(ub.z), da);
            da = fmaf(bfhi(ua.z), bfhi(ub.z), da);
            da = fmaf(bflo(ua.w), bflo(ub.w), da);
            da = fmaf(bfhi(ua.w), bfhi(ub.w), da);
        }
        da += __shfl_xor(da, 1);
        da += __shfl_xor(da, 2);
        if (p == 0) s_sim[d] = da;
    }

#pragma unroll
    for (int p = 0; p < 2; ++p)
#pragma unroll
        for (int q = 0; q < 4; ++q)
            acc[p][q] = f32x4{0.f, 0.f, 0.f, 0.f};
#pragma unroll
    for (int kk = 0; kk < 8; ++kk) {
        const int ko = kk * 32 + ((lane >> 4) << 3);
        bf16x8 y0 = __builtin_bit_cast(bf16x8, *(const uint4*)(sF2 + r0 * LDK + ko));
        bf16x8 y1 = __builtin_bit_cast(bf16x8, *(const uint4*)(sF2 + r1 * LDK + ko));
        bf16x8 bf[4];
#pragma unroll
        for (int ct = 0; ct < 4; ++ct)
            bf[ct] = __builtin_bit_cast(bf16x8,
                *(const uint4*)(bv + (((kk << 2) + ct) * 64 + lane) * 8));
#pragma unroll
        for (int ct = 0; ct < 4; ++ct) {
            acc[0][ct] = __builtin_amdgcn_mfma_f32_16x16x32_bf16(y0, bf[ct], acc[0][ct], 0, 0, 0);
            acc[1][ct] = __builtin_amdgcn_mfma_f32_16x16x32_bf16(y1, bf[ct], acc[1][ct], 0, 0, 0);
        }
    }
    storeD(sF1, w << 6, lane, acc);       // v over feat1 (all sF1 readers done at B2)
    __syncthreads();                      // B3: v + s_sim visible

    // ---- combine with inline softmax; coalesced out ----
#pragma unroll
    for (int pass = 0; pass < 3; ++pass) {
        int u = tid + (pass << 8);        // 0..767, active < 640
        if (u < 640) {
            int r  = u >> 5;
            int ch = (u & 31) << 3;
            float o[8] = {0.f, 0.f, 0.f, 0.f, 0.f, 0.f, 0.f, 0.f};
            if (r == 16) {
                const uint16_t* vb = &sF1[ch];
#pragma unroll
                for (int ss = 0; ss < TT; ++ss)
                    acc8(o, *(const uint4*)(vb + ss * LDK), 0.05f);
            } else {
                int cnt = c_CNT[r];
                int off = c_OFF[r];
                float m = -1e30f;
#pragma unroll
                for (int j = 0; j < 4; ++j)
                    if (j < cnt) m = fmaxf(m, s_sim[off + j]);
                float e[4] = {0.f, 0.f, 0.f, 0.f};
                float sum = 0.f;
#pragma unroll
                for (int j = 0; j < 4; ++j)
                    if (j < cnt) { e[j] = __expf(s_sim[off + j] - m); sum += e[j]; }
                float inv = 1.f / sum;
#pragma unroll
                for (int j = 0; j < 4; ++j)
                    if (j < cnt)
                        acc8(o, *(const uint4*)&sF1[c_COLS[r][j] * LDK + ch], e[j] * inv);
            }
            float* op = outg + base + (size_t)r * CC + ch;
            *(float4*)op       = make_float4(o[0], o[1], o[2], o[3]);
            *(float4*)(op + 4) = make_float4(o[4], o[5], o[6], o[7]);
        }
    }
}

extern "C" void kernel_launch(void* const* d_in, const int* in_sizes, int n_in,
                              void* d_out, int out_size, void* d_ws, size_t ws_size,
                              hipStream_t stream) {
    const float* feat1 = (const float*)d_in[0];
    const float* feat2 = (const float*)d_in[1];
    const float* Wq    = (const float*)d_in[2];
    const float* Wk    = (const float*)d_in[3];
    const float* Wv    = (const float*)d_in[4];
    uint16_t* mqkT = (uint16_t*)d_ws;          // 128 KB
    uint16_t* wvb  = mqkT + CC * CC;           // 128 KB
    uint16_t* BqS  = wvb  + CC * CC;           // 128 KB (swizzled)
    uint16_t* BvS  = BqS  + CC * CC;           // 128 KB (swizzled)

    prep1_kernel<<<CC, CC, 0, stream>>>(Wq, Wk, Wv, mqkT, wvb);
    prep2_kernel<<<64, NT, 0, stream>>>(mqkT, wvb, BqS, BvS);
    attn_main<<<NBATCH, NT, 0, stream>>>(feat1, feat2, BqS, BvS, (float*)d_out);
}